// Round 1
// baseline (63.545 us; speedup 1.0000x reference)
//
#include <hip/hip_runtime.h>

#define NUM_CLASSES 80

__global__ __launch_bounds__(256) void targets_kernel(
    const float* __restrict__ ann, const float* __restrict__ anchors,
    float* __restrict__ cls, float* __restrict__ reg, float* __restrict__ states,
    int A, int N) {
#pragma clang fp contract(off)
  __shared__ float4 sbox[64];
  __shared__ float sarea[64];
  __shared__ int slabel[64];
  __shared__ int sinfo[256];

  const int b = blockIdx.y;
  const int a0 = blockIdx.x * 256;
  const int tid = threadIdx.x;

  // Stage this batch's 64 GT boxes into LDS (x1,y1,x2,y2), area, label.
  if (tid < N) {
    const float* p = ann + ((size_t)b * N + tid) * 5;
    float x1 = p[0], y1 = p[1], x2 = p[2], y2 = p[3];
    sbox[tid] = make_float4(x1, y1, x2, y2);
    sarea[tid] = (x2 - x1) * (y2 - y1);
    slabel[tid] = (int)p[4];
  }
  __syncthreads();

  const int a = a0 + tid;
  const bool valid = (a < A);
  const int aidx = valid ? a : 0;
  const float4 anc = reinterpret_cast<const float4*>(anchors)[aidx];
  const float area_a = (anc.z - anc.x) * (anc.w - anc.y);

  // IoU argmax over the 64 boxes; op order matches the JAX/np reference
  // exactly (contraction disabled) so argmax is bit-identical.
  float best = -3.402823466e38f;
  int bestj = 0;
  #pragma unroll 8
  for (int j = 0; j < N; ++j) {
    float4 bx = sbox[j];
    float iw = fminf(anc.z, bx.z) - fmaxf(anc.x, bx.x);
    float ih = fminf(anc.w, bx.w) - fmaxf(anc.y, bx.y);
    float inter = fmaxf(iw, 0.0f) * fmaxf(ih, 0.0f);
    float uni = fmaxf(area_a + sarea[j] - inter, 1e-8f);
    float iou = inter / uni;
    if (iou > best) { best = iou; bestj = j; }
  }

  const bool positive = best >= 0.5f;
  const bool ignore = (best > 0.4f) && !positive;
  const float state = positive ? 1.0f : (ignore ? -1.0f : 0.0f);

  if (valid) {
    float4 bt = sbox[bestj];
    float aw = anc.z - anc.x;
    float ah = anc.w - anc.y;
    float4 r;
    r.x = ((bt.x - anc.x) / aw) / 0.2f;
    r.y = ((bt.y - anc.y) / ah) / 0.2f;
    r.z = ((bt.z - anc.z) / aw) / 0.2f;
    r.w = ((bt.w - anc.w) / ah) / 0.2f;
    reinterpret_cast<float4*>(reg)[(size_t)b * A + a] = r;
    states[(size_t)b * A + a] = state;
  }
  sinfo[tid] = positive ? slabel[bestj] : -1;
  __syncthreads();

  // Phase 2: fully-coalesced one-hot cls writes for this block's anchors.
  const int nvalid = min(256, A - a0);
  float4* clsv = reinterpret_cast<float4*>(cls + ((size_t)b * A + a0) * NUM_CLASSES);
  const int total = nvalid * (NUM_CLASSES / 4);
  for (int it = tid; it < total; it += 256) {
    int al = it / (NUM_CLASSES / 4);
    int w = it - al * (NUM_CLASSES / 4);
    int lab = sinfo[al];  // -1 if not positive
    int c0 = w * 4;
    float4 v;
    v.x = (lab == c0 + 0) ? 1.0f : 0.0f;
    v.y = (lab == c0 + 1) ? 1.0f : 0.0f;
    v.z = (lab == c0 + 2) ? 1.0f : 0.0f;
    v.w = (lab == c0 + 3) ? 1.0f : 0.0f;
    clsv[it] = v;
  }
}

extern "C" void kernel_launch(void* const* d_in, const int* in_sizes, int n_in,
                              void* d_out, int out_size, void* d_ws, size_t ws_size,
                              hipStream_t stream) {
  const float* ann = (const float*)d_in[0];
  const float* anchors = (const float*)d_in[1];

  const int A = in_sizes[1] / 4;                                   // 120000
  const int B = (int)((long long)out_size / ((long long)A * (NUM_CLASSES + 5)));  // 8
  const int N = in_sizes[0] / (B * 5);                             // 64

  float* out = (float*)d_out;
  float* cls = out;
  float* reg = cls + (size_t)B * A * NUM_CLASSES;
  float* states = reg + (size_t)B * A * 4;

  dim3 grid((A + 255) / 256, B);
  targets_kernel<<<grid, 256, 0, stream>>>(ann, anchors, cls, reg, states, A, N);
}